// Round 15
// baseline (4082.948 us; speedup 1.0000x reference)
//
#include <hip/hip_runtime.h>

// ---------------- problem constants ----------------
constexpr int N  = 325;   // nodes
constexpr int B  = 64;    // batch
constexpr int T  = 12;    // encoder steps
constexpr int HZ = 12;    // decoder horizon
constexpr int U  = 64;    // rnn units
constexpr int BN = B * N; // 20800 rows

// SS = [S ; S^2] stacked: rows [0,325)=S, [336,661)=S^2 (42 tiles of 16)
constexpr int SSTIL = 42;
constexpr int SSKC  = 11;   // K chunks of 32 (K padded 325->352)
constexpr int XST   = 364;  // u32 stride per feature column in diffuse LDS

typedef __attribute__((ext_vector_type(8))) short short8;
typedef __attribute__((ext_vector_type(4))) float floatx4;

// bf16 round-to-nearest-even + hi/lo split helpers
__device__ inline unsigned short f2bf(float f) {
    unsigned u = __float_as_uint(f);
    u += 0x7fff + ((u >> 16) & 1);
    return (unsigned short)(u >> 16);
}
__device__ inline unsigned pack_hilo(float v) {
    const unsigned short hi = f2bf(v);
    const float hif = __uint_as_float(((unsigned)hi) << 16);
    const unsigned short lo = f2bf(v - hif);
    return (unsigned)hi | ((unsigned)lo << 16);
}
__device__ inline void unpack8(const uint4 u0, const uint4 u1,
                               short8& h, short8& l) {
    const unsigned uu[8] = {u0.x, u0.y, u0.z, u0.w, u1.x, u1.y, u1.z, u1.w};
    #pragma unroll
    for (int j = 0; j < 8; ++j) {
        h[j] = (short)(uu[j] & 0xffffu);
        l[j] = (short)(uu[j] >> 16);
    }
}

// ---------------- setup kernels ----------------

__global__ void zero_kernel(unsigned* __restrict__ p, long n) {
    long i = (long)blockIdx.x * blockDim.x + threadIdx.x;
    const long stride = (long)gridDim.x * blockDim.x;
    for (; i < n; i += stride) p[i] = 0u;
}

// S2 = S @ S (fp32). One block per output row.
__global__ __launch_bounds__(256)
void s2_build(const float* __restrict__ S, float* __restrict__ S2)
{
    const int m = blockIdx.x;
    __shared__ float srow[N];
    for (int i = threadIdx.x; i < N; i += 256) srow[i] = S[m * N + i];
    __syncthreads();
    for (int c = threadIdx.x; c < N; c += 256) {
        float a = 0.f;
        for (int k = 0; k < N; ++k) a += srow[k] * S[k * N + c];
        S2[m * N + c] = a;
    }
}

// Prepack SS=[S;S2] into MFMA A-fragments (bf16 hi/lo).
__global__ __launch_bounds__(64)
void prepack_ss(const float* __restrict__ S, const float* __restrict__ S2,
                short* __restrict__ ssh, short* __restrict__ ssl)
{
    const int t = blockIdx.x, kc = blockIdx.y, lane = threadIdx.x;
    const int quad = lane >> 4, l15 = lane & 15;
    short8 hv, lv;
    #pragma unroll
    for (int j = 0; j < 8; ++j) {
        const int m = t * 16 + l15;
        const int k = kc * 32 + quad * 8 + j;
        float v = 0.f;
        if (k < N) {
            if (m < N) v = S[m * N + k];
            else if (m >= 336 && m < 336 + N) v = S2[(m - 336) * N + k];
        }
        const unsigned short hb = f2bf(v);
        hv[j] = (short)hb;
        lv[j] = (short)f2bf(v - __uint_as_float(((unsigned)hb) << 16));
    }
    const size_t off = ((size_t)(t * SSKC + kc) * 64 + lane);
    ((short8*)ssh)[off] = hv;
    ((short8*)ssl)[off] = lv;
}

// Prepack weights into MFMA B-fragment order, bf16 hi/lo, for K-layout
// [ z0-slices (Z0KC*32, from x/h, fold W0'=W0-W2) | y1 (F, W1) | y2 (F, 2*W2) ]
// zero rows elsewhere.
__global__ __launch_bounds__(64)
void prepack_w(const float* __restrict__ W, short* __restrict__ Wh,
               short* __restrict__ Wl, int F, int Nout, int NT, int Z0KC)
{
    const int kc = blockIdx.x, n = blockIdx.y, lane = threadIdx.x;
    const int quad = lane >> 4, l15 = lane & 15;
    short8 hv, lv;
    #pragma unroll
    for (int j = 0; j < 8; ++j) {
        const int p   = kc * 32 + quad * 8 + j;
        const int col = n * 16 + l15;
        float w = 0.f;
        if (p < Z0KC * 32) {
            const int f = p;
            if (f < F)
                w = W[(size_t)f * Nout + col] - W[(size_t)(2 * F + f) * Nout + col];
        } else {
            const int q = p - Z0KC * 32;
            if (q < F)
                w = W[(size_t)(F + q) * Nout + col];
            else if (q < 2 * F)
                w = 2.f * W[(size_t)(2 * F + (q - F)) * Nout + col];
        }
        const unsigned short hb = f2bf(w);
        hv[j] = (short)hb;
        lv[j] = (short)f2bf(w - __uint_as_float(((unsigned)hb) << 16));
    }
    const size_t off = ((size_t)(kc * NT + n) * 64 + lane);
    ((short8*)Wh)[off] = hv;
    ((short8*)Wl)[off] = lv;
}

// ---------------- z0 A-fragment builder (bit-identical to old pack path) ----
template<int DIN, int F, bool RM, bool ZV>
__device__ __forceinline__ void z0_frag(const float* __restrict__ x,
    const float* __restrict__ h, const float* __restrict__ ru,
    int row, int kc, int quad, short8& ah, short8& al)
{
    float v[8];
    if constexpr (ZV) {   // DIN==64, F==128: aligned float4 path
        const int k0 = kc * 32 + quad * 8;
        if (k0 < 64) {
            const float4 a = *(const float4*)&x[(size_t)row * 64 + k0];
            const float4 b = *(const float4*)&x[(size_t)row * 64 + k0 + 4];
            v[0]=a.x; v[1]=a.y; v[2]=a.z; v[3]=a.w;
            v[4]=b.x; v[5]=b.y; v[6]=b.z; v[7]=b.w;
        } else {
            const int kk = k0 - 64;
            float4 a = *(const float4*)&h[(size_t)row * 64 + kk];
            float4 b = *(const float4*)&h[(size_t)row * 64 + kk + 4];
            if constexpr (RM) {
                const float4 ra = *(const float4*)&ru[(size_t)row * 128 + kk];
                const float4 rb = *(const float4*)&ru[(size_t)row * 128 + kk + 4];
                a.x *= ra.x; a.y *= ra.y; a.z *= ra.z; a.w *= ra.w;
                b.x *= rb.x; b.y *= rb.y; b.z *= rb.z; b.w *= rb.w;
            }
            v[0]=a.x; v[1]=a.y; v[2]=a.z; v[3]=a.w;
            v[4]=b.x; v[5]=b.y; v[6]=b.z; v[7]=b.w;
        }
    } else {
        #pragma unroll
        for (int j = 0; j < 8; ++j) {
            const int k = kc * 32 + quad * 8 + j;
            float t = 0.f;
            if (k < DIN) t = x[(size_t)row * DIN + k];
            else if (k < F) {
                t = h[(size_t)row * 64 + (k - DIN)];
                if constexpr (RM) t *= ru[(size_t)row * 128 + (k - DIN)];
            }
            v[j] = t;
        }
    }
    #pragma unroll
    for (int j = 0; j < 8; ++j) {
        const unsigned u = pack_hilo(v[j]);
        ah[j] = (short)(u & 0xffffu);
        al[j] = (short)(u >> 16);
    }
}

// ---------------- diffusion GEMM body (y-only zcat) ----------------
// Y = SS @ X_b for one (batch, 32-col window at c0, M-half mh).
// NTHR threads (896: all 42 tiles, mh=0; 448: 21 tiles of half mh).
// Staging writes ONLY LDS, so the M-split duplicates reads only.
// Epilogue writes y1|y2 (pitch YP): y1 at col, y2 at F+col.
// DUAL (encoder L0 cell): columns col>=DIN are h0 columns shared with the
// L1 cell of the same dispatch — mirror the SAME packed bits into zdual
// (pitch 256, F_B=128) at col-DIN. Bit-identical to recomputation.
template<int DIN, int F, int YP, bool RMUL, bool VEC, int NTHR, bool DUAL = false>
__device__ __forceinline__ void diffuse_body(
    const short8* __restrict__ ssh, const short8* __restrict__ ssl,
    const float* __restrict__ x, const float* __restrict__ h,
    const float* __restrict__ ru, unsigned* __restrict__ zcat,
    int c0, int b, int mh, unsigned* __restrict__ xls,
    unsigned* __restrict__ zdual = nullptr)
{
    const int tid = threadIdx.x, wave = tid >> 6, lane = tid & 63;
    const int quad = lane >> 4, l15 = lane & 15;

    if constexpr (VEC) {
        for (int idx4 = tid; idx4 < 352 * 8; idx4 += NTHR) {
            const int n = idx4 >> 3, f = (idx4 & 7) * 4, gf = c0 + f;
            uint4 pk = make_uint4(0u, 0u, 0u, 0u);
            if (n < N) {
                const int row = b * N + n;
                float4 v;
                if (gf < DIN) {
                    v = *(const float4*)&x[(size_t)row * DIN + gf];
                } else {
                    v = *(const float4*)&h[(size_t)row * U + (gf - DIN)];
                    if (RMUL) {
                        const float4 rv = *(const float4*)&ru[(size_t)row * 128 + (gf - DIN)];
                        v.x *= rv.x; v.y *= rv.y; v.z *= rv.z; v.w *= rv.w;
                    }
                }
                pk.x = pack_hilo(v.x); pk.y = pack_hilo(v.y);
                pk.z = pack_hilo(v.z); pk.w = pack_hilo(v.w);
            }
            xls[(f + 0) * XST + n] = pk.x;
            xls[(f + 1) * XST + n] = pk.y;
            xls[(f + 2) * XST + n] = pk.z;
            xls[(f + 3) * XST + n] = pk.w;
        }
    } else {
        for (int idx = tid; idx < 352 * 32; idx += NTHR) {
            const int n = idx >> 5, f = idx & 31, gf = c0 + f;
            unsigned u = 0u;
            if (n < N && gf < F) {
                const int row = b * N + n;
                float v;
                if (gf < DIN) {
                    v = x[(size_t)row * DIN + gf];
                } else {
                    v = h[(size_t)row * U + (gf - DIN)];
                    if (RMUL) v *= ru[(size_t)row * 128 + (gf - DIN)];
                }
                u = pack_hilo(v);
            }
            xls[f * XST + n] = u;
        }
    }
    __syncthreads();

    const int tb = mh * 21 + wave * 3;  // 3 row tiles per wave

    floatx4 acc[3][2];
    #pragma unroll
    for (int i = 0; i < 3; ++i)
        #pragma unroll
        for (int n = 0; n < 2; ++n)
            acc[i][n] = (floatx4){0.f, 0.f, 0.f, 0.f};

    short8 cah[3], cal[3], nah[3], nal[3];
    #pragma unroll
    for (int i = 0; i < 3; ++i) {
        const size_t fo = (size_t)((tb + i) * SSKC) * 64 + lane;
        cah[i] = ssh[fo]; cal[i] = ssl[fo];
    }
    for (int kc = 0; kc < SSKC; ++kc) {
        if (kc + 1 < SSKC) {
            #pragma unroll
            for (int i = 0; i < 3; ++i) {
                const size_t fo = (size_t)((tb + i) * SSKC + kc + 1) * 64 + lane;
                nah[i] = ssh[fo]; nal[i] = ssl[fo];
            }
        }
        short8 bh[2], bl[2];
        const int koff = kc * 32 + quad * 8;
        #pragma unroll
        for (int n = 0; n < 2; ++n) {
            const uint4 u0 = *(const uint4*)&xls[(n * 16 + l15) * XST + koff];
            const uint4 u1 = *(const uint4*)&xls[(n * 16 + l15) * XST + koff + 4];
            unpack8(u0, u1, bh[n], bl[n]);
        }
        #pragma unroll
        for (int i = 0; i < 3; ++i)
            #pragma unroll
            for (int n = 0; n < 2; ++n) {
                acc[i][n] = __builtin_amdgcn_mfma_f32_16x16x32_bf16(cah[i], bh[n], acc[i][n], 0, 0, 0);
                acc[i][n] = __builtin_amdgcn_mfma_f32_16x16x32_bf16(cah[i], bl[n], acc[i][n], 0, 0, 0);
                acc[i][n] = __builtin_amdgcn_mfma_f32_16x16x32_bf16(cal[i], bh[n], acc[i][n], 0, 0, 0);
            }
        if (kc + 1 < SSKC) {
            #pragma unroll
            for (int i = 0; i < 3; ++i) { cah[i] = nah[i]; cal[i] = nal[i]; }
        }
    }

    #pragma unroll
    for (int i = 0; i < 3; ++i) {
        const int t = tb + i;
        #pragma unroll
        for (int n = 0; n < 2; ++n) {
            const int col = c0 + n * 16 + l15;
            if (col >= F) continue;
            #pragma unroll
            for (int r = 0; r < 4; ++r) {
                const int m = t * 16 + quad * 4 + r;
                const unsigned pv = pack_hilo(acc[i][n][r]);
                if (m < N) {
                    zcat[(size_t)(b * N + m) * YP + col] = pv;
                    if constexpr (DUAL) {
                        const int j = col - DIN;
                        if (j >= 0)
                            zdual[(size_t)(b * N + m) * 256 + j] = pv;
                    }
                } else if (m >= 336 && m < 336 + N) {
                    zcat[(size_t)(b * N + (m - 336)) * YP + F + col] = pv;
                    if constexpr (DUAL) {
                        const int j = col - DIN;
                        if (j >= 0)
                            zdual[(size_t)(b * N + (m - 336)) * 256 + 128 + j] = pv;
                    }
                }
            }
        }
    }
}

// ---------------- dense GEMM bodies (z0 from globals, y from zcat) ----------

// Gate: ru = sigmoid([z0|y1|y2] @ Wg + b). nb = col-tile base (0 or 4).
template<int DIN, int F, int Z0KC, int YKC, bool ZV>
__device__ __forceinline__ void gate_body(const unsigned* __restrict__ zcat,
    const float* __restrict__ x, const float* __restrict__ h,
    const short8* __restrict__ Wh, const short8* __restrict__ Wl,
    const float* __restrict__ bias, float* __restrict__ ruout, int bx, int nb)
{
    constexpr int YP = YKC * 32, NT = 4;
    const int tid = threadIdx.x, wave = tid >> 6, lane = tid & 63;
    const int quad = lane >> 4, l15 = lane & 15;
    const int row0 = bx * 64 + wave * 16;
    const int row = row0 + l15;

    floatx4 acc[NT];
    #pragma unroll
    for (int n = 0; n < NT; ++n) {
        const float bv = bias[(nb + n) * 16 + l15];
        acc[n] = (floatx4){bv, bv, bv, bv};
    }
    for (int kc = 0; kc < Z0KC; ++kc) {
        short8 ahi, alo;
        z0_frag<DIN, F, false, ZV>(x, h, nullptr, row, kc, quad, ahi, alo);
        const short8* __restrict__ wh = Wh + (size_t)(kc * 8 + nb) * 64 + lane;
        const short8* __restrict__ wl = Wl + (size_t)(kc * 8 + nb) * 64 + lane;
        #pragma unroll
        for (int n = 0; n < NT; ++n) {
            const short8 bh = wh[n * 64], bl = wl[n * 64];
            acc[n] = __builtin_amdgcn_mfma_f32_16x16x32_bf16(ahi, bh, acc[n], 0, 0, 0);
            acc[n] = __builtin_amdgcn_mfma_f32_16x16x32_bf16(ahi, bl, acc[n], 0, 0, 0);
            acc[n] = __builtin_amdgcn_mfma_f32_16x16x32_bf16(alo, bh, acc[n], 0, 0, 0);
        }
    }
    const unsigned* __restrict__ zrow = zcat + (size_t)row * YP + quad * 8;
    for (int kc = 0; kc < YKC; ++kc) {
        const uint4* p = (const uint4*)(zrow + kc * 32);
        short8 ahi, alo;
        unpack8(p[0], p[1], ahi, alo);
        const short8* __restrict__ wh = Wh + (size_t)((Z0KC + kc) * 8 + nb) * 64 + lane;
        const short8* __restrict__ wl = Wl + (size_t)((Z0KC + kc) * 8 + nb) * 64 + lane;
        #pragma unroll
        for (int n = 0; n < NT; ++n) {
            const short8 bh = wh[n * 64], bl = wl[n * 64];
            acc[n] = __builtin_amdgcn_mfma_f32_16x16x32_bf16(ahi, bh, acc[n], 0, 0, 0);
            acc[n] = __builtin_amdgcn_mfma_f32_16x16x32_bf16(ahi, bl, acc[n], 0, 0, 0);
            acc[n] = __builtin_amdgcn_mfma_f32_16x16x32_bf16(alo, bh, acc[n], 0, 0, 0);
        }
    }
    #pragma unroll
    for (int n = 0; n < NT; ++n) {
        const int col = (nb + n) * 16 + l15;
        #pragma unroll
        for (int r = 0; r < 4; ++r) {
            const int rw = row0 + quad * 4 + r;
            ruout[(size_t)rw * 128 + col] = 1.f / (1.f + __expf(-acc[n][r]));
        }
    }
}

// Candidate: c = tanh([z0r|y1|y2] @ Wc + b); hout = u*h + (1-u)*c. nb = 0/2.
template<int DIN, int F, int Z0KC, int YKC, bool ZV>
__device__ __forceinline__ void cand_body(const unsigned* __restrict__ zcat,
    const float* __restrict__ x, const float* __restrict__ h,
    const float* __restrict__ ru, const short8* __restrict__ Wh,
    const short8* __restrict__ Wl, const float* __restrict__ bias,
    float* __restrict__ hout, int bx, int nb)
{
    constexpr int YP = YKC * 32, NT = 2;
    const int tid = threadIdx.x, wave = tid >> 6, lane = tid & 63;
    const int quad = lane >> 4, l15 = lane & 15;
    const int row0 = bx * 64 + wave * 16;
    const int row = row0 + l15;

    floatx4 acc[NT];
    #pragma unroll
    for (int n = 0; n < NT; ++n) {
        const float bv = bias[(nb + n) * 16 + l15];
        acc[n] = (floatx4){bv, bv, bv, bv};
    }
    for (int kc = 0; kc < Z0KC; ++kc) {
        short8 ahi, alo;
        z0_frag<DIN, F, true, ZV>(x, h, ru, row, kc, quad, ahi, alo);
        const short8* __restrict__ wh = Wh + (size_t)(kc * 4 + nb) * 64 + lane;
        const short8* __restrict__ wl = Wl + (size_t)(kc * 4 + nb) * 64 + lane;
        #pragma unroll
        for (int n = 0; n < NT; ++n) {
            const short8 bh = wh[n * 64], bl = wl[n * 64];
            acc[n] = __builtin_amdgcn_mfma_f32_16x16x32_bf16(ahi, bh, acc[n], 0, 0, 0);
            acc[n] = __builtin_amdgcn_mfma_f32_16x16x32_bf16(ahi, bl, acc[n], 0, 0, 0);
            acc[n] = __builtin_amdgcn_mfma_f32_16x16x32_bf16(alo, bh, acc[n], 0, 0, 0);
        }
    }
    const unsigned* __restrict__ zrow = zcat + (size_t)row * YP + quad * 8;
    for (int kc = 0; kc < YKC; ++kc) {
        const uint4* p = (const uint4*)(zrow + kc * 32);
        short8 ahi, alo;
        unpack8(p[0], p[1], ahi, alo);
        const short8* __restrict__ wh = Wh + (size_t)((Z0KC + kc) * 4 + nb) * 64 + lane;
        const short8* __restrict__ wl = Wl + (size_t)((Z0KC + kc) * 4 + nb) * 64 + lane;
        #pragma unroll
        for (int n = 0; n < NT; ++n) {
            const short8 bh = wh[n * 64], bl = wl[n * 64];
            acc[n] = __builtin_amdgcn_mfma_f32_16x16x32_bf16(ahi, bh, acc[n], 0, 0, 0);
            acc[n] = __builtin_amdgcn_mfma_f32_16x16x32_bf16(ahi, bl, acc[n], 0, 0, 0);
            acc[n] = __builtin_amdgcn_mfma_f32_16x16x32_bf16(alo, bh, acc[n], 0, 0, 0);
        }
    }
    #pragma unroll
    for (int n = 0; n < NT; ++n) {
        const int col = (nb + n) * 16 + l15;
        #pragma unroll
        for (int r = 0; r < 4; ++r) {
            const int rw = row0 + quad * 4 + r;
            const float c  = tanhf(acc[n][r]);
            const float ug = ru[(size_t)rw * 128 + 64 + col];  // u = ru[:,64:]
            const float hv = h[(size_t)rw * 64 + col];
            hout[(size_t)rw * 64 + col] = ug * hv + (1.f - ug) * c;
        }
    }
}

// ---------------- solo kernels ----------------

// M-split diffuse: 448 thr, blockIdx.z = M-half. Full-GPU for small chunk counts.
template<int DIN, int F, int YP, bool RMUL, int C0OFF, bool VEC>
__global__ __launch_bounds__(448, 3)
void diffuse_solo(const short8* __restrict__ ssh, const short8* __restrict__ ssl,
                  const float* __restrict__ x, const float* __restrict__ h,
                  const float* __restrict__ ru, unsigned* __restrict__ zcat)
{
    __shared__ __align__(16) unsigned xls[32 * XST];
    diffuse_body<DIN, F, YP, RMUL, VEC, 448>(ssh, ssl, x, h, ru, zcat,
                                             C0OFF + blockIdx.x * 32, blockIdx.y,
                                             blockIdx.z, xls);
}

template<int DIN, int F, int Z0KC, int YKC, bool ZV>
__global__ __launch_bounds__(256)
void gate_cell(const unsigned* __restrict__ zcat, const float* __restrict__ x,
               const float* __restrict__ h, const short8* __restrict__ Wh,
               const short8* __restrict__ Wl, const float* __restrict__ bias,
               float* __restrict__ ru)
{
    gate_body<DIN, F, Z0KC, YKC, ZV>(zcat, x, h, Wh, Wl, bias, ru,
                                     blockIdx.x, blockIdx.y * 4);
}

template<int DIN, int F, int Z0KC, int YKC, bool ZV>
__global__ __launch_bounds__(256)
void cand_cell(const unsigned* __restrict__ zcat, const float* __restrict__ x,
               const float* __restrict__ h, const float* __restrict__ ru,
               const short8* __restrict__ Wh, const short8* __restrict__ Wl,
               const float* __restrict__ bias, float* __restrict__ hout)
{
    cand_body<DIN, F, Z0KC, YKC, ZV>(zcat, x, h, ru, Wh, Wl, bias, hout,
                                     blockIdx.x, blockIdx.y * 2);
}

// Candidate + fused projection (decoder layer 1, L1 geometry). NT=4 unsplit.
__global__ __launch_bounds__(256)
void cand_proj(const unsigned* __restrict__ zcat, const float* __restrict__ x,
               const float* __restrict__ h, const float* __restrict__ ru,
               const short8* __restrict__ Wh, const short8* __restrict__ Wl,
               const float* __restrict__ bias, float* __restrict__ hout,
               const float* __restrict__ pW, const float* __restrict__ pb,
               float* __restrict__ outp, float* __restrict__ dec_in)
{
    constexpr int Z0KC = 4, YKC = 8, YP = 256, NT = 4;
    const int tid = threadIdx.x, wave = tid >> 6, lane = tid & 63;
    const int quad = lane >> 4, l15 = lane & 15;
    const int row0 = blockIdx.x * 64 + wave * 16;
    const int row = row0 + l15;

    floatx4 acc[NT];
    #pragma unroll
    for (int n = 0; n < NT; ++n) {
        const float bv = bias[n * 16 + l15];
        acc[n] = (floatx4){bv, bv, bv, bv};
    }
    for (int kc = 0; kc < Z0KC; ++kc) {
        short8 ahi, alo;
        z0_frag<64, 128, true, true>(x, h, ru, row, kc, quad, ahi, alo);
        const short8* __restrict__ wh = Wh + (size_t)(kc * 4) * 64 + lane;
        const short8* __restrict__ wl = Wl + (size_t)(kc * 4) * 64 + lane;
        #pragma unroll
        for (int n = 0; n < NT; ++n) {
            const short8 bh = wh[n * 64], bl = wl[n * 64];
            acc[n] = __builtin_amdgcn_mfma_f32_16x16x32_bf16(ahi, bh, acc[n], 0, 0, 0);
            acc[n] = __builtin_amdgcn_mfma_f32_16x16x32_bf16(ahi, bl, acc[n], 0, 0, 0);
            acc[n] = __builtin_amdgcn_mfma_f32_16x16x32_bf16(alo, bh, acc[n], 0, 0, 0);
        }
    }
    const unsigned* __restrict__ zrow = zcat + (size_t)row * YP + quad * 8;
    for (int kc = 0; kc < YKC; ++kc) {
        const uint4* p = (const uint4*)(zrow + kc * 32);
        short8 ahi, alo;
        unpack8(p[0], p[1], ahi, alo);
        const short8* __restrict__ wh = Wh + (size_t)((Z0KC + kc) * 4) * 64 + lane;
        const short8* __restrict__ wl = Wl + (size_t)((Z0KC + kc) * 4) * 64 + lane;
        #pragma unroll
        for (int n = 0; n < NT; ++n) {
            const short8 bh = wh[n * 64], bl = wl[n * 64];
            acc[n] = __builtin_amdgcn_mfma_f32_16x16x32_bf16(ahi, bh, acc[n], 0, 0, 0);
            acc[n] = __builtin_amdgcn_mfma_f32_16x16x32_bf16(ahi, bl, acc[n], 0, 0, 0);
            acc[n] = __builtin_amdgcn_mfma_f32_16x16x32_bf16(alo, bh, acc[n], 0, 0, 0);
        }
    }
    float pr[4] = {0.f, 0.f, 0.f, 0.f};
    #pragma unroll
    for (int n = 0; n < NT; ++n) {
        const int col = n * 16 + l15;
        const float pw = pW[col];
        #pragma unroll
        for (int r = 0; r < 4; ++r) {
            const int rw = row0 + quad * 4 + r;
            const float c  = tanhf(acc[n][r]);
            const float ug = ru[(size_t)rw * 128 + 64 + col];
            const float hv = h[(size_t)rw * 64 + col];
            const float hn = ug * hv + (1.f - ug) * c;
            hout[(size_t)rw * 64 + col] = hn;
            pr[r] += hn * pw;
        }
    }
    #pragma unroll
    for (int r = 0; r < 4; ++r) {
        float v = pr[r];
        v += __shfl_xor(v, 1); v += __shfl_xor(v, 2);
        v += __shfl_xor(v, 4); v += __shfl_xor(v, 8);
        if (l15 == 0) {
            const int rw = row0 + quad * 4 + r;
            const float o = v + pb[0];
            outp[rw]   = o;
            dec_in[rw] = o;
        }
    }
}

// ---------------- duo kernels ----------------

struct DuoDP {
    const short8 *ssh, *ssl;
    const float *xA, *hA, *ruA; unsigned* zA;
    const float *xB, *hB, *ruB; unsigned* zB;
    int cA;      // chunk count for cell A
    int coA;     // column offset (elements) for cell A chunks
    int coB;     // column offset (elements) for cell B chunks
};

// Encoder GATE duo: cell A = L0 (DIN=2,F=66) FULL, with DUAL write mirroring
// its h0-column y's into zcatB (they are bit-identical to L1's x-column y's,
// since both diffuse the same H0 buffer). Cell B computes ONLY its h1 columns
// (cols 64..127). 3 + 2 = 5 chunks (was 7).
__global__ __launch_bounds__(896, 7)
void diffuse_duo_g(DuoDP P)
{
    __shared__ __align__(16) unsigned xls[32 * XST];
    if ((int)blockIdx.x < 3)
        diffuse_body<2, 66, 160, false, false, 896, true>(
            P.ssh, P.ssl, P.xA, P.hA, nullptr, P.zA,
            blockIdx.x * 32, blockIdx.y, 0, xls, P.zB);
    else
        diffuse_body<64, 128, 256, false, true, 896>(
            P.ssh, P.ssl, P.xB, P.hB, nullptr, P.zB,
            64 + (blockIdx.x - 3) * 32, blockIdx.y, 0, xls);
}

// Encoder CAND duo (h-cols only, 4 chunks): M-split 448-thread form.
__global__ __launch_bounds__(448, 3)
void diffuse_duo_c(DuoDP P)
{
    __shared__ __align__(16) unsigned xls[32 * XST];
    if ((int)blockIdx.x < P.cA)
        diffuse_body<2, 66, 160, true, false, 448>(P.ssh, P.ssl, P.xA, P.hA,
                                                   P.ruA, P.zA,
                                                   P.coA + blockIdx.x * 32,
                                                   blockIdx.y, blockIdx.z, xls);
    else
        diffuse_body<64, 128, 256, true, true, 448>(P.ssh, P.ssl, P.xB, P.hB,
                                                    P.ruB, P.zB,
                                                    P.coB + (blockIdx.x - P.cA) * 32,
                                                    blockIdx.y, blockIdx.z, xls);
}

// Decoder slot-1 duo: A = L0 gate-diffusion (DIN=1,F=65, all cols),
// B = L1 gate-diffusion h-columns (depend only on previous step's h1).
// M-split 448-thread form.
__global__ __launch_bounds__(448, 3)
void diffuse_duo_dec(DuoDP P)
{
    __shared__ __align__(16) unsigned xls[32 * XST];
    if ((int)blockIdx.x < P.cA)
        diffuse_body<1, 65, 160, false, false, 448>(P.ssh, P.ssl, P.xA, P.hA,
                                                    nullptr, P.zA,
                                                    P.coA + blockIdx.x * 32,
                                                    blockIdx.y, blockIdx.z, xls);
    else
        diffuse_body<64, 128, 256, false, true, 448>(P.ssh, P.ssl, P.xB, P.hB,
                                                     nullptr, P.zB,
                                                     P.coB + (blockIdx.x - P.cA) * 32,
                                                     blockIdx.y, blockIdx.z, xls);
}

struct DuoGP {
    const unsigned* zA; const float *xA, *hA;
    const short8 *WhA, *WlA; const float* bA; float* ruA;
    const unsigned* zB; const float *xB, *hB;
    const short8 *WhB, *WlB; const float* bB; float* ruB;
};

__global__ __launch_bounds__(256)
void gate_duo(DuoGP P)
{
    if (blockIdx.z == 0)
        gate_body<2, 66, 3, 5, false>(P.zA, P.xA, P.hA, P.WhA, P.WlA, P.bA,
                                      P.ruA, blockIdx.x, blockIdx.y * 4);
    else
        gate_body<64, 128, 4, 8, true>(P.zB, P.xB, P.hB, P.WhB, P.WlB, P.bB,
                                       P.ruB, blockIdx.x, blockIdx.y * 4);
}

struct DuoCP {
    const unsigned* zA; const float *xA, *hA, *ruA;
    const short8 *WhA, *WlA; const float* bA; float* hoA;
    const unsigned* zB; const float *xB, *hB, *ruB;
    const short8 *WhB, *WlB; const float* bB; float* hoB;
};

__global__ __launch_bounds__(256)
void cand_duo(DuoCP P)
{
    if (blockIdx.z == 0)
        cand_body<2, 66, 3, 5, false>(P.zA, P.xA, P.hA, P.ruA, P.WhA, P.WlA,
                                      P.bA, P.hoA, blockIdx.x, blockIdx.y * 2);
    else
        cand_body<64, 128, 4, 8, true>(P.zB, P.xB, P.hB, P.ruB, P.WhB, P.WlB,
                                       P.bB, P.hoB, blockIdx.x, blockIdx.y * 2);
}

// ---------------- host launcher ----------------

extern "C" void kernel_launch(void* const* d_in, const int* in_sizes, int n_in,
                              void* d_out, int out_size, void* d_ws, size_t ws_size,
                              hipStream_t stream)
{
    const float* inputs = (const float*)d_in[0];
    const float* S      = (const float*)d_in[1];
    const float* Wt[4][4];
    for (int l = 0; l < 4; ++l)
        for (int j = 0; j < 4; ++j)
            Wt[l][j] = (const float*)d_in[2 + l * 4 + j];
    const float* pW = (const float*)d_in[18];
    const float* pb = (const float*)d_in[19];
    float* out = (float*)d_out;

    // workspace layout (ping-pong h; y-only zcat)
    float*    ws     = (float*)d_ws;
    float*    H0[2]  = {ws, ws + (size_t)BN * U};
    float*    H1[2]  = {ws + 2 * (size_t)BN * U, ws + 3 * (size_t)BN * U};
    float*    dec_in = ws + 4 * (size_t)BN * U;            // BN
    float*    ruA    = dec_in + BN;                        // BN*128
    float*    ruB    = ruA + (size_t)BN * 128;             // BN*128
    unsigned* zcatA  = (unsigned*)(ruB + (size_t)BN * 128);  // BN*160
    unsigned* zcatB  = zcatA + (size_t)BN * 160;             // BN*256
    float*    S2     = (float*)(zcatB + (size_t)BN * 256);   // N*N
    char*     pp     = (char*)(S2 + (size_t)N * N);
    pp = (char*)(((uintptr_t)pp + 15) & ~(uintptr_t)15);

    short* ssh = (short*)pp;                       // 42*11*64*8 shorts
    short* ssl = ssh + (size_t)SSTIL * SSKC * 64 * 8;
    char*  wpbase = (char*)(ssl + (size_t)SSTIL * SSKC * 64 * 8);

    // K layouts: [z0 pad | y1 | y2 pad]; L0: 3+5 kc = 256, L1: 4+8 kc = 384
    const int Fs[4]   = {66, 128, 65, 128};
    const int KPs[4]  = {256, 384, 256, 384};
    const int Z0s[4]  = {3, 4, 3, 4};
    short *Wgh[4], *Wgl[4], *Wch[4], *Wcl[4];
    size_t off = 0;
    for (int l = 0; l < 4; ++l) {
        const size_t ge = (size_t)KPs[l] * 128, ce = (size_t)KPs[l] * 64;
        Wgh[l] = (short*)(wpbase + off); off += ge * 2;
        Wgl[l] = (short*)(wpbase + off); off += ge * 2;
        Wch[l] = (short*)(wpbase + off); off += ce * 2;
        Wcl[l] = (short*)(wpbase + off); off += ce * 2;
    }

    // zero state + zcat (first-use NaN-safety; pads stay finite thereafter)
    const long zn = (long)BN * (4 * U) + BN + (long)BN * 256 + (long)BN * (160 + 256);
    zero_kernel<<<2048, 256, 0, stream>>>((unsigned*)ws, zn);

    s2_build<<<N, 256, 0, stream>>>(S, S2);
    prepack_ss<<<dim3(SSTIL, SSKC), 64, 0, stream>>>(S, S2, ssh, ssl);
    for (int l = 0; l < 4; ++l) {
        prepack_w<<<dim3(KPs[l] / 32, 8), 64, 0, stream>>>(Wt[l][0], Wgh[l], Wgl[l],
                                                           Fs[l], 128, 8, Z0s[l]);
        prepack_w<<<dim3(KPs[l] / 32, 4), 64, 0, stream>>>(Wt[l][2], Wch[l], Wcl[l],
                                                           Fs[l], 64, 4, Z0s[l]);
    }

    const short8* SSH = (const short8*)ssh;
    const short8* SSL = (const short8*)ssl;
    int p0 = 0, p1 = 0;

    // -------- encoder: software-pipelined (cell0 step s || cell1 step s-1) ----
    for (int s = 0; s <= T; ++s) {
        const float* x0 = inputs + (size_t)s * BN * 2;
        const bool a = (s < T), b1 = (s >= 1);
        if (a && b1) {
            // gate diffusion: cell A full (dual-writes shared H0 y's into zcatB),
            // cell B h1-cols only. 5 chunks.
            DuoDP dp{SSH, SSL, x0, H0[p0], nullptr, zcatA,
                     H0[p0], H1[p1], nullptr, zcatB, 3, 0, 0};
            diffuse_duo_g<<<dim3(5, B), 896, 0, stream>>>(dp);
            DuoGP gp{zcatA, x0, H0[p0], (short8*)Wgh[0], (short8*)Wgl[0], Wt[0][1], ruA,
                     zcatB, H0[p0], H1[p1], (short8*)Wgh[1], (short8*)Wgl[1], Wt[1][1], ruB};
            gate_duo<<<dim3(BN / 64, 2, 2), 256, 0, stream>>>(gp);
            // cand diffusion: h-cols only (x-col y's reused from gate pass)
            DuoDP dp2{SSH, SSL, x0, H0[p0], ruA, zcatA,
                      H0[p0], H1[p1], ruB, zcatB, 2, 2, 64};
            diffuse_duo_c<<<dim3(4, B, 2), 448, 0, stream>>>(dp2);
            DuoCP cp{zcatA, x0, H0[p0], ruA, (short8*)Wch[0], (short8*)Wcl[0], Wt[0][3], H0[p0 ^ 1],
                     zcatB, H0[p0], H1[p1], ruB, (short8*)Wch[1], (short8*)Wcl[1], Wt[1][3], H1[p1 ^ 1]};
            cand_duo<<<dim3(BN / 64, 2, 2), 256, 0, stream>>>(cp);
            p0 ^= 1; p1 ^= 1;
        } else if (a) {  // s == 0: cell0 solo; h0 == 0 so h-col y's are zero
            // (matching the zero-initialized zcatA bit-for-bit) -> only chunk 0
            // of the gate diffusion is needed, and the cand diffusion (r*h = 0)
            // is skipped entirely.
            diffuse_solo<2, 66, 160, false, 0, false><<<dim3(1, B, 2), 448, 0, stream>>>(
                SSH, SSL, x0, H0[p0], nullptr, zcatA);
            gate_cell<2, 66, 3, 5, false><<<dim3(BN / 64, 2), 256, 0, stream>>>(
                zcatA, x0, H0[p0], (short8*)Wgh[0], (short8*)Wgl[0], Wt[0][1], ruA);
            cand_cell<2, 66, 3, 5, false><<<dim3(BN / 64, 2), 256, 0, stream>>>(
                zcatA, x0, H0[p0], ruA, (short8*)Wch[0], (short8*)Wcl[0], Wt[0][3], H0[p0 ^ 1]);
            p0 ^= 1;
        } else {         // s == T: cell1 drain
            diffuse_solo<64, 128, 256, false, 0, true><<<dim3(4, B, 2), 448, 0, stream>>>(
                SSH, SSL, H0[p0], H1[p1], nullptr, zcatB);
            gate_cell<64, 128, 4, 8, true><<<dim3(BN / 64, 2), 256, 0, stream>>>(
                zcatB, H0[p0], H1[p1], (short8*)Wgh[1], (short8*)Wgl[1], Wt[1][1], ruB);
            diffuse_solo<64, 128, 256, true, 64, true><<<dim3(2, B, 2), 448, 0, stream>>>(
                SSH, SSL, H0[p0], H1[p1], ruB, zcatB);
            cand_cell<64, 128, 4, 8, true><<<dim3(BN / 64, 2), 256, 0, stream>>>(
                zcatB, H0[p0], H1[p1], ruB, (short8*)Wch[1], (short8*)Wcl[1], Wt[1][3], H1[p1 ^ 1]);
            p1 ^= 1;
        }
    }

    // -------- decoder: slot1 = [L0 gate-diff ∥ L1 h-col gate-diff] --------
    // L0 lives in zcatA (pitch 160), L1 in zcatB (pitch 256).
    for (int hz = 0; hz < HZ; ++hz) {
        DuoDP dd{SSH, SSL, dec_in, H0[p0], nullptr, zcatA,
                 H0[p0], H1[p1], nullptr, zcatB, 3, 0, 64};
        diffuse_duo_dec<<<dim3(5, B, 2), 448, 0, stream>>>(dd);
        gate_cell<1, 65, 3, 5, false><<<dim3(BN / 64, 2), 256, 0, stream>>>(
            zcatA, dec_in, H0[p0], (short8*)Wgh[2], (short8*)Wgl[2], Wt[2][1], ruA);
        // L0 cand diffusion: h-cols only (cols 1..64)
        diffuse_solo<1, 65, 160, true, 1, false><<<dim3(2, B, 2), 448, 0, stream>>>(
            SSH, SSL, dec_in, H0[p0], ruA, zcatA);
        cand_cell<1, 65, 3, 5, false><<<dim3(BN / 64, 2), 256, 0, stream>>>(
            zcatA, dec_in, H0[p0], ruA, (short8*)Wch[2], (short8*)Wcl[2], Wt[2][3], H0[p0 ^ 1]);
        p0 ^= 1;
        // L1 gate-diff: x-cols only (h-cols hoisted into slot 1)
        diffuse_solo<64, 128, 256, false, 0, true><<<dim3(2, B, 2), 448, 0, stream>>>(
            SSH, SSL, H0[p0], H1[p1], nullptr, zcatB);
        gate_cell<64, 128, 4, 8, true><<<dim3(BN / 64, 2), 256, 0, stream>>>(
            zcatB, H0[p0], H1[p1], (short8*)Wgh[3], (short8*)Wgl[3], Wt[3][1], ruA);
        // L1 cand diffusion: h-cols only
        diffuse_solo<64, 128, 256, true, 64, true><<<dim3(2, B, 2), 448, 0, stream>>>(
            SSH, SSL, H0[p0], H1[p1], ruA, zcatB);
        cand_proj<<<BN / 64, 256, 0, stream>>>(
            zcatB, H0[p0], H1[p1], ruA, (short8*)Wch[3], (short8*)Wcl[3], Wt[3][3],
            H1[p1 ^ 1], pW, pb, out + (size_t)hz * BN, dec_in);
        p1 ^= 1;
    }
}

// Round 16
// 3694.113 us; speedup vs baseline: 1.1053x; 1.1053x over previous
//
#include <hip/hip_runtime.h>

// ---------------- problem constants ----------------
constexpr int N  = 325;   // nodes
constexpr int B  = 64;    // batch
constexpr int T  = 12;    // encoder steps
constexpr int HZ = 12;    // decoder horizon
constexpr int U  = 64;    // rnn units
constexpr int BN = B * N; // 20800 rows

// SS = [S ; S^2] stacked: rows [0,325)=S, [336,661)=S^2 (42 tiles of 16)
constexpr int SSTIL = 42;
constexpr int SSKC  = 11;   // K chunks of 32 (K padded 325->352)
constexpr int XST   = 364;  // u32 stride per feature column in diffuse LDS

typedef __attribute__((ext_vector_type(8))) short short8;
typedef __attribute__((ext_vector_type(4))) float floatx4;

// bf16 round-to-nearest-even + hi/lo split helpers
__device__ inline unsigned short f2bf(float f) {
    unsigned u = __float_as_uint(f);
    u += 0x7fff + ((u >> 16) & 1);
    return (unsigned short)(u >> 16);
}
__device__ inline unsigned pack_hilo(float v) {
    const unsigned short hi = f2bf(v);
    const float hif = __uint_as_float(((unsigned)hi) << 16);
    const unsigned short lo = f2bf(v - hif);
    return (unsigned)hi | ((unsigned)lo << 16);
}
__device__ inline void unpack8(const uint4 u0, const uint4 u1,
                               short8& h, short8& l) {
    const unsigned uu[8] = {u0.x, u0.y, u0.z, u0.w, u1.x, u1.y, u1.z, u1.w};
    #pragma unroll
    for (int j = 0; j < 8; ++j) {
        h[j] = (short)(uu[j] & 0xffffu);
        l[j] = (short)(uu[j] >> 16);
    }
}

// ---------------- setup kernels ----------------

__global__ void zero_kernel(unsigned* __restrict__ p, long n) {
    long i = (long)blockIdx.x * blockDim.x + threadIdx.x;
    const long stride = (long)gridDim.x * blockDim.x;
    for (; i < n; i += stride) p[i] = 0u;
}

// S2 = S @ S (fp32). One block per output row.
__global__ __launch_bounds__(256)
void s2_build(const float* __restrict__ S, float* __restrict__ S2)
{
    const int m = blockIdx.x;
    __shared__ float srow[N];
    for (int i = threadIdx.x; i < N; i += 256) srow[i] = S[m * N + i];
    __syncthreads();
    for (int c = threadIdx.x; c < N; c += 256) {
        float a = 0.f;
        for (int k = 0; k < N; ++k) a += srow[k] * S[k * N + c];
        S2[m * N + c] = a;
    }
}

// Prepack SS=[S;S2] into MFMA A-fragments (bf16 hi/lo).
__global__ __launch_bounds__(64)
void prepack_ss(const float* __restrict__ S, const float* __restrict__ S2,
                short* __restrict__ ssh, short* __restrict__ ssl)
{
    const int t = blockIdx.x, kc = blockIdx.y, lane = threadIdx.x;
    const int quad = lane >> 4, l15 = lane & 15;
    short8 hv, lv;
    #pragma unroll
    for (int j = 0; j < 8; ++j) {
        const int m = t * 16 + l15;
        const int k = kc * 32 + quad * 8 + j;
        float v = 0.f;
        if (k < N) {
            if (m < N) v = S[m * N + k];
            else if (m >= 336 && m < 336 + N) v = S2[(m - 336) * N + k];
        }
        const unsigned short hb = f2bf(v);
        hv[j] = (short)hb;
        lv[j] = (short)f2bf(v - __uint_as_float(((unsigned)hb) << 16));
    }
    const size_t off = ((size_t)(t * SSKC + kc) * 64 + lane);
    ((short8*)ssh)[off] = hv;
    ((short8*)ssl)[off] = lv;
}

// Prepack weights into MFMA B-fragment order, bf16 hi/lo, for K-layout
// [ z0-slices (Z0KC*32, from x/h, fold W0'=W0-W2) | y1 (F, W1) | y2 (F, 2*W2) ]
// zero rows elsewhere.
__global__ __launch_bounds__(64)
void prepack_w(const float* __restrict__ W, short* __restrict__ Wh,
               short* __restrict__ Wl, int F, int Nout, int NT, int Z0KC)
{
    const int kc = blockIdx.x, n = blockIdx.y, lane = threadIdx.x;
    const int quad = lane >> 4, l15 = lane & 15;
    short8 hv, lv;
    #pragma unroll
    for (int j = 0; j < 8; ++j) {
        const int p   = kc * 32 + quad * 8 + j;
        const int col = n * 16 + l15;
        float w = 0.f;
        if (p < Z0KC * 32) {
            const int f = p;
            if (f < F)
                w = W[(size_t)f * Nout + col] - W[(size_t)(2 * F + f) * Nout + col];
        } else {
            const int q = p - Z0KC * 32;
            if (q < F)
                w = W[(size_t)(F + q) * Nout + col];
            else if (q < 2 * F)
                w = 2.f * W[(size_t)(2 * F + (q - F)) * Nout + col];
        }
        const unsigned short hb = f2bf(w);
        hv[j] = (short)hb;
        lv[j] = (short)f2bf(w - __uint_as_float(((unsigned)hb) << 16));
    }
    const size_t off = ((size_t)(kc * NT + n) * 64 + lane);
    ((short8*)Wh)[off] = hv;
    ((short8*)Wl)[off] = lv;
}

// ---------------- z0 A-fragment builder (bit-identical to old pack path) ----
template<int DIN, int F, bool RM, bool ZV>
__device__ __forceinline__ void z0_frag(const float* __restrict__ x,
    const float* __restrict__ h, const float* __restrict__ ru,
    int row, int kc, int quad, short8& ah, short8& al)
{
    float v[8];
    if constexpr (ZV) {   // DIN==64, F==128: aligned float4 path
        const int k0 = kc * 32 + quad * 8;
        if (k0 < 64) {
            const float4 a = *(const float4*)&x[(size_t)row * 64 + k0];
            const float4 b = *(const float4*)&x[(size_t)row * 64 + k0 + 4];
            v[0]=a.x; v[1]=a.y; v[2]=a.z; v[3]=a.w;
            v[4]=b.x; v[5]=b.y; v[6]=b.z; v[7]=b.w;
        } else {
            const int kk = k0 - 64;
            float4 a = *(const float4*)&h[(size_t)row * 64 + kk];
            float4 b = *(const float4*)&h[(size_t)row * 64 + kk + 4];
            if constexpr (RM) {
                const float4 ra = *(const float4*)&ru[(size_t)row * 128 + kk];
                const float4 rb = *(const float4*)&ru[(size_t)row * 128 + kk + 4];
                a.x *= ra.x; a.y *= ra.y; a.z *= ra.z; a.w *= ra.w;
                b.x *= rb.x; b.y *= rb.y; b.z *= rb.z; b.w *= rb.w;
            }
            v[0]=a.x; v[1]=a.y; v[2]=a.z; v[3]=a.w;
            v[4]=b.x; v[5]=b.y; v[6]=b.z; v[7]=b.w;
        }
    } else {
        #pragma unroll
        for (int j = 0; j < 8; ++j) {
            const int k = kc * 32 + quad * 8 + j;
            float t = 0.f;
            if (k < DIN) t = x[(size_t)row * DIN + k];
            else if (k < F) {
                t = h[(size_t)row * 64 + (k - DIN)];
                if constexpr (RM) t *= ru[(size_t)row * 128 + (k - DIN)];
            }
            v[j] = t;
        }
    }
    #pragma unroll
    for (int j = 0; j < 8; ++j) {
        const unsigned u = pack_hilo(v[j]);
        ah[j] = (short)(u & 0xffffu);
        al[j] = (short)(u >> 16);
    }
}

// ---------------- diffusion GEMM body (y-only zcat) ----------------
// Y = SS @ X_b for one (batch, 32-col window at c0, M-half mh).
// NTHR threads (896: all 42 tiles, mh=0; 448: 21 tiles of half mh).
// Staging writes ONLY LDS, so the M-split duplicates reads only.
// Epilogue writes y1|y2 (pitch YP): y1 at col, y2 at F+col.
template<int DIN, int F, int YP, bool RMUL, bool VEC, int NTHR>
__device__ __forceinline__ void diffuse_body(
    const short8* __restrict__ ssh, const short8* __restrict__ ssl,
    const float* __restrict__ x, const float* __restrict__ h,
    const float* __restrict__ ru, unsigned* __restrict__ zcat,
    int c0, int b, int mh, unsigned* __restrict__ xls)
{
    const int tid = threadIdx.x, wave = tid >> 6, lane = tid & 63;
    const int quad = lane >> 4, l15 = lane & 15;

    if constexpr (VEC) {
        for (int idx4 = tid; idx4 < 352 * 8; idx4 += NTHR) {
            const int n = idx4 >> 3, f = (idx4 & 7) * 4, gf = c0 + f;
            uint4 pk = make_uint4(0u, 0u, 0u, 0u);
            if (n < N) {
                const int row = b * N + n;
                float4 v;
                if (gf < DIN) {
                    v = *(const float4*)&x[(size_t)row * DIN + gf];
                } else {
                    v = *(const float4*)&h[(size_t)row * U + (gf - DIN)];
                    if (RMUL) {
                        const float4 rv = *(const float4*)&ru[(size_t)row * 128 + (gf - DIN)];
                        v.x *= rv.x; v.y *= rv.y; v.z *= rv.z; v.w *= rv.w;
                    }
                }
                pk.x = pack_hilo(v.x); pk.y = pack_hilo(v.y);
                pk.z = pack_hilo(v.z); pk.w = pack_hilo(v.w);
            }
            xls[(f + 0) * XST + n] = pk.x;
            xls[(f + 1) * XST + n] = pk.y;
            xls[(f + 2) * XST + n] = pk.z;
            xls[(f + 3) * XST + n] = pk.w;
        }
    } else {
        for (int idx = tid; idx < 352 * 32; idx += NTHR) {
            const int n = idx >> 5, f = idx & 31, gf = c0 + f;
            unsigned u = 0u;
            if (n < N && gf < F) {
                const int row = b * N + n;
                float v;
                if (gf < DIN) {
                    v = x[(size_t)row * DIN + gf];
                } else {
                    v = h[(size_t)row * U + (gf - DIN)];
                    if (RMUL) v *= ru[(size_t)row * 128 + (gf - DIN)];
                }
                u = pack_hilo(v);
            }
            xls[f * XST + n] = u;
        }
    }
    __syncthreads();

    const int tb = mh * 21 + wave * 3;  // 3 row tiles per wave

    floatx4 acc[3][2];
    #pragma unroll
    for (int i = 0; i < 3; ++i)
        #pragma unroll
        for (int n = 0; n < 2; ++n)
            acc[i][n] = (floatx4){0.f, 0.f, 0.f, 0.f};

    short8 cah[3], cal[3], nah[3], nal[3];
    #pragma unroll
    for (int i = 0; i < 3; ++i) {
        const size_t fo = (size_t)((tb + i) * SSKC) * 64 + lane;
        cah[i] = ssh[fo]; cal[i] = ssl[fo];
    }
    for (int kc = 0; kc < SSKC; ++kc) {
        if (kc + 1 < SSKC) {
            #pragma unroll
            for (int i = 0; i < 3; ++i) {
                const size_t fo = (size_t)((tb + i) * SSKC + kc + 1) * 64 + lane;
                nah[i] = ssh[fo]; nal[i] = ssl[fo];
            }
        }
        short8 bh[2], bl[2];
        const int koff = kc * 32 + quad * 8;
        #pragma unroll
        for (int n = 0; n < 2; ++n) {
            const uint4 u0 = *(const uint4*)&xls[(n * 16 + l15) * XST + koff];
            const uint4 u1 = *(const uint4*)&xls[(n * 16 + l15) * XST + koff + 4];
            unpack8(u0, u1, bh[n], bl[n]);
        }
        #pragma unroll
        for (int i = 0; i < 3; ++i)
            #pragma unroll
            for (int n = 0; n < 2; ++n) {
                acc[i][n] = __builtin_amdgcn_mfma_f32_16x16x32_bf16(cah[i], bh[n], acc[i][n], 0, 0, 0);
                acc[i][n] = __builtin_amdgcn_mfma_f32_16x16x32_bf16(cah[i], bl[n], acc[i][n], 0, 0, 0);
                acc[i][n] = __builtin_amdgcn_mfma_f32_16x16x32_bf16(cal[i], bh[n], acc[i][n], 0, 0, 0);
            }
        if (kc + 1 < SSKC) {
            #pragma unroll
            for (int i = 0; i < 3; ++i) { cah[i] = nah[i]; cal[i] = nal[i]; }
        }
    }

    #pragma unroll
    for (int i = 0; i < 3; ++i) {
        const int t = tb + i;
        #pragma unroll
        for (int n = 0; n < 2; ++n) {
            const int col = c0 + n * 16 + l15;
            if (col >= F) continue;
            #pragma unroll
            for (int r = 0; r < 4; ++r) {
                const int m = t * 16 + quad * 4 + r;
                if (m < N)
                    zcat[(size_t)(b * N + m) * YP + col] = pack_hilo(acc[i][n][r]);
                else if (m >= 336 && m < 336 + N)
                    zcat[(size_t)(b * N + (m - 336)) * YP + F + col] = pack_hilo(acc[i][n][r]);
            }
        }
    }
}

// ---------------- dense GEMM bodies (z0 from globals, y from zcat) ----------

// Gate: ru = sigmoid([z0|y1|y2] @ Wg + b). nb = col-tile base (0 or 4).
template<int DIN, int F, int Z0KC, int YKC, bool ZV>
__device__ __forceinline__ void gate_body(const unsigned* __restrict__ zcat,
    const float* __restrict__ x, const float* __restrict__ h,
    const short8* __restrict__ Wh, const short8* __restrict__ Wl,
    const float* __restrict__ bias, float* __restrict__ ruout, int bx, int nb)
{
    constexpr int YP = YKC * 32, NT = 4;
    const int tid = threadIdx.x, wave = tid >> 6, lane = tid & 63;
    const int quad = lane >> 4, l15 = lane & 15;
    const int row0 = bx * 64 + wave * 16;
    const int row = row0 + l15;

    floatx4 acc[NT];
    #pragma unroll
    for (int n = 0; n < NT; ++n) {
        const float bv = bias[(nb + n) * 16 + l15];
        acc[n] = (floatx4){bv, bv, bv, bv};
    }
    for (int kc = 0; kc < Z0KC; ++kc) {
        short8 ahi, alo;
        z0_frag<DIN, F, false, ZV>(x, h, nullptr, row, kc, quad, ahi, alo);
        const short8* __restrict__ wh = Wh + (size_t)(kc * 8 + nb) * 64 + lane;
        const short8* __restrict__ wl = Wl + (size_t)(kc * 8 + nb) * 64 + lane;
        #pragma unroll
        for (int n = 0; n < NT; ++n) {
            const short8 bh = wh[n * 64], bl = wl[n * 64];
            acc[n] = __builtin_amdgcn_mfma_f32_16x16x32_bf16(ahi, bh, acc[n], 0, 0, 0);
            acc[n] = __builtin_amdgcn_mfma_f32_16x16x32_bf16(ahi, bl, acc[n], 0, 0, 0);
            acc[n] = __builtin_amdgcn_mfma_f32_16x16x32_bf16(alo, bh, acc[n], 0, 0, 0);
        }
    }
    const unsigned* __restrict__ zrow = zcat + (size_t)row * YP + quad * 8;
    for (int kc = 0; kc < YKC; ++kc) {
        const uint4* p = (const uint4*)(zrow + kc * 32);
        short8 ahi, alo;
        unpack8(p[0], p[1], ahi, alo);
        const short8* __restrict__ wh = Wh + (size_t)((Z0KC + kc) * 8 + nb) * 64 + lane;
        const short8* __restrict__ wl = Wl + (size_t)((Z0KC + kc) * 8 + nb) * 64 + lane;
        #pragma unroll
        for (int n = 0; n < NT; ++n) {
            const short8 bh = wh[n * 64], bl = wl[n * 64];
            acc[n] = __builtin_amdgcn_mfma_f32_16x16x32_bf16(ahi, bh, acc[n], 0, 0, 0);
            acc[n] = __builtin_amdgcn_mfma_f32_16x16x32_bf16(ahi, bl, acc[n], 0, 0, 0);
            acc[n] = __builtin_amdgcn_mfma_f32_16x16x32_bf16(alo, bh, acc[n], 0, 0, 0);
        }
    }
    #pragma unroll
    for (int n = 0; n < NT; ++n) {
        const int col = (nb + n) * 16 + l15;
        #pragma unroll
        for (int r = 0; r < 4; ++r) {
            const int rw = row0 + quad * 4 + r;
            ruout[(size_t)rw * 128 + col] = 1.f / (1.f + __expf(-acc[n][r]));
        }
    }
}

// Candidate: c = tanh([z0r|y1|y2] @ Wc + b); hout = u*h + (1-u)*c. nb = 0/2.
template<int DIN, int F, int Z0KC, int YKC, bool ZV>
__device__ __forceinline__ void cand_body(const unsigned* __restrict__ zcat,
    const float* __restrict__ x, const float* __restrict__ h,
    const float* __restrict__ ru, const short8* __restrict__ Wh,
    const short8* __restrict__ Wl, const float* __restrict__ bias,
    float* __restrict__ hout, int bx, int nb)
{
    constexpr int YP = YKC * 32, NT = 2;
    const int tid = threadIdx.x, wave = tid >> 6, lane = tid & 63;
    const int quad = lane >> 4, l15 = lane & 15;
    const int row0 = bx * 64 + wave * 16;
    const int row = row0 + l15;

    floatx4 acc[NT];
    #pragma unroll
    for (int n = 0; n < NT; ++n) {
        const float bv = bias[(nb + n) * 16 + l15];
        acc[n] = (floatx4){bv, bv, bv, bv};
    }
    for (int kc = 0; kc < Z0KC; ++kc) {
        short8 ahi, alo;
        z0_frag<DIN, F, true, ZV>(x, h, ru, row, kc, quad, ahi, alo);
        const short8* __restrict__ wh = Wh + (size_t)(kc * 4 + nb) * 64 + lane;
        const short8* __restrict__ wl = Wl + (size_t)(kc * 4 + nb) * 64 + lane;
        #pragma unroll
        for (int n = 0; n < NT; ++n) {
            const short8 bh = wh[n * 64], bl = wl[n * 64];
            acc[n] = __builtin_amdgcn_mfma_f32_16x16x32_bf16(ahi, bh, acc[n], 0, 0, 0);
            acc[n] = __builtin_amdgcn_mfma_f32_16x16x32_bf16(ahi, bl, acc[n], 0, 0, 0);
            acc[n] = __builtin_amdgcn_mfma_f32_16x16x32_bf16(alo, bh, acc[n], 0, 0, 0);
        }
    }
    const unsigned* __restrict__ zrow = zcat + (size_t)row * YP + quad * 8;
    for (int kc = 0; kc < YKC; ++kc) {
        const uint4* p = (const uint4*)(zrow + kc * 32);
        short8 ahi, alo;
        unpack8(p[0], p[1], ahi, alo);
        const short8* __restrict__ wh = Wh + (size_t)((Z0KC + kc) * 4 + nb) * 64 + lane;
        const short8* __restrict__ wl = Wl + (size_t)((Z0KC + kc) * 4 + nb) * 64 + lane;
        #pragma unroll
        for (int n = 0; n < NT; ++n) {
            const short8 bh = wh[n * 64], bl = wl[n * 64];
            acc[n] = __builtin_amdgcn_mfma_f32_16x16x32_bf16(ahi, bh, acc[n], 0, 0, 0);
            acc[n] = __builtin_amdgcn_mfma_f32_16x16x32_bf16(ahi, bl, acc[n], 0, 0, 0);
            acc[n] = __builtin_amdgcn_mfma_f32_16x16x32_bf16(alo, bh, acc[n], 0, 0, 0);
        }
    }
    #pragma unroll
    for (int n = 0; n < NT; ++n) {
        const int col = (nb + n) * 16 + l15;
        #pragma unroll
        for (int r = 0; r < 4; ++r) {
            const int rw = row0 + quad * 4 + r;
            const float c  = tanhf(acc[n][r]);
            const float ug = ru[(size_t)rw * 128 + 64 + col];  // u = ru[:,64:]
            const float hv = h[(size_t)rw * 64 + col];
            hout[(size_t)rw * 64 + col] = ug * hv + (1.f - ug) * c;
        }
    }
}

// ---------------- solo kernels ----------------

// M-split diffuse: 448 thr, blockIdx.z = M-half. Full-GPU for small chunk counts.
template<int DIN, int F, int YP, bool RMUL, int C0OFF, bool VEC>
__global__ __launch_bounds__(448, 3)
void diffuse_solo(const short8* __restrict__ ssh, const short8* __restrict__ ssl,
                  const float* __restrict__ x, const float* __restrict__ h,
                  const float* __restrict__ ru, unsigned* __restrict__ zcat)
{
    __shared__ __align__(16) unsigned xls[32 * XST];
    diffuse_body<DIN, F, YP, RMUL, VEC, 448>(ssh, ssl, x, h, ru, zcat,
                                             C0OFF + blockIdx.x * 32, blockIdx.y,
                                             blockIdx.z, xls);
}

template<int DIN, int F, int Z0KC, int YKC, bool ZV>
__global__ __launch_bounds__(256)
void gate_cell(const unsigned* __restrict__ zcat, const float* __restrict__ x,
               const float* __restrict__ h, const short8* __restrict__ Wh,
               const short8* __restrict__ Wl, const float* __restrict__ bias,
               float* __restrict__ ru)
{
    gate_body<DIN, F, Z0KC, YKC, ZV>(zcat, x, h, Wh, Wl, bias, ru,
                                     blockIdx.x, blockIdx.y * 4);
}

template<int DIN, int F, int Z0KC, int YKC, bool ZV>
__global__ __launch_bounds__(256)
void cand_cell(const unsigned* __restrict__ zcat, const float* __restrict__ x,
               const float* __restrict__ h, const float* __restrict__ ru,
               const short8* __restrict__ Wh, const short8* __restrict__ Wl,
               const float* __restrict__ bias, float* __restrict__ hout)
{
    cand_body<DIN, F, Z0KC, YKC, ZV>(zcat, x, h, ru, Wh, Wl, bias, hout,
                                     blockIdx.x, blockIdx.y * 2);
}

// Candidate + fused projection (decoder layer 1, L1 geometry). NT=4 unsplit.
__global__ __launch_bounds__(256)
void cand_proj(const unsigned* __restrict__ zcat, const float* __restrict__ x,
               const float* __restrict__ h, const float* __restrict__ ru,
               const short8* __restrict__ Wh, const short8* __restrict__ Wl,
               const float* __restrict__ bias, float* __restrict__ hout,
               const float* __restrict__ pW, const float* __restrict__ pb,
               float* __restrict__ outp, float* __restrict__ dec_in)
{
    constexpr int Z0KC = 4, YKC = 8, YP = 256, NT = 4;
    const int tid = threadIdx.x, wave = tid >> 6, lane = tid & 63;
    const int quad = lane >> 4, l15 = lane & 15;
    const int row0 = blockIdx.x * 64 + wave * 16;
    const int row = row0 + l15;

    floatx4 acc[NT];
    #pragma unroll
    for (int n = 0; n < NT; ++n) {
        const float bv = bias[n * 16 + l15];
        acc[n] = (floatx4){bv, bv, bv, bv};
    }
    for (int kc = 0; kc < Z0KC; ++kc) {
        short8 ahi, alo;
        z0_frag<64, 128, true, true>(x, h, ru, row, kc, quad, ahi, alo);
        const short8* __restrict__ wh = Wh + (size_t)(kc * 4) * 64 + lane;
        const short8* __restrict__ wl = Wl + (size_t)(kc * 4) * 64 + lane;
        #pragma unroll
        for (int n = 0; n < NT; ++n) {
            const short8 bh = wh[n * 64], bl = wl[n * 64];
            acc[n] = __builtin_amdgcn_mfma_f32_16x16x32_bf16(ahi, bh, acc[n], 0, 0, 0);
            acc[n] = __builtin_amdgcn_mfma_f32_16x16x32_bf16(ahi, bl, acc[n], 0, 0, 0);
            acc[n] = __builtin_amdgcn_mfma_f32_16x16x32_bf16(alo, bh, acc[n], 0, 0, 0);
        }
    }
    const unsigned* __restrict__ zrow = zcat + (size_t)row * YP + quad * 8;
    for (int kc = 0; kc < YKC; ++kc) {
        const uint4* p = (const uint4*)(zrow + kc * 32);
        short8 ahi, alo;
        unpack8(p[0], p[1], ahi, alo);
        const short8* __restrict__ wh = Wh + (size_t)((Z0KC + kc) * 4) * 64 + lane;
        const short8* __restrict__ wl = Wl + (size_t)((Z0KC + kc) * 4) * 64 + lane;
        #pragma unroll
        for (int n = 0; n < NT; ++n) {
            const short8 bh = wh[n * 64], bl = wl[n * 64];
            acc[n] = __builtin_amdgcn_mfma_f32_16x16x32_bf16(ahi, bh, acc[n], 0, 0, 0);
            acc[n] = __builtin_amdgcn_mfma_f32_16x16x32_bf16(ahi, bl, acc[n], 0, 0, 0);
            acc[n] = __builtin_amdgcn_mfma_f32_16x16x32_bf16(alo, bh, acc[n], 0, 0, 0);
        }
    }
    float pr[4] = {0.f, 0.f, 0.f, 0.f};
    #pragma unroll
    for (int n = 0; n < NT; ++n) {
        const int col = n * 16 + l15;
        const float pw = pW[col];
        #pragma unroll
        for (int r = 0; r < 4; ++r) {
            const int rw = row0 + quad * 4 + r;
            const float c  = tanhf(acc[n][r]);
            const float ug = ru[(size_t)rw * 128 + 64 + col];
            const float hv = h[(size_t)rw * 64 + col];
            const float hn = ug * hv + (1.f - ug) * c;
            hout[(size_t)rw * 64 + col] = hn;
            pr[r] += hn * pw;
        }
    }
    #pragma unroll
    for (int r = 0; r < 4; ++r) {
        float v = pr[r];
        v += __shfl_xor(v, 1); v += __shfl_xor(v, 2);
        v += __shfl_xor(v, 4); v += __shfl_xor(v, 8);
        if (l15 == 0) {
            const int rw = row0 + quad * 4 + r;
            const float o = v + pb[0];
            outp[rw]   = o;
            dec_in[rw] = o;
        }
    }
}

// ---------------- duo kernels ----------------

struct DuoDP {
    const short8 *ssh, *ssl;
    const float *xA, *hA, *ruA; unsigned* zA;
    const float *xB, *hB, *ruB; unsigned* zB;
    int cA;      // chunk count for cell A
    int coA;     // column offset (elements) for cell A chunks
    int coB;     // column offset (elements) for cell B chunks
};

// Encoder GATE duo: A = L0 (DIN=2,F=66), B = L1 (DIN=64,F=128).
// 7 chunks -> merged 896-thread form (staging-dominated; round-9/14 proven).
__global__ __launch_bounds__(896, 7)
void diffuse_duo_g(DuoDP P)
{
    __shared__ __align__(16) unsigned xls[32 * XST];
    if ((int)blockIdx.x < P.cA)
        diffuse_body<2, 66, 160, false, false, 896>(P.ssh, P.ssl, P.xA, P.hA,
                                                    nullptr, P.zA,
                                                    P.coA + blockIdx.x * 32,
                                                    blockIdx.y, 0, xls);
    else
        diffuse_body<64, 128, 256, false, true, 896>(P.ssh, P.ssl, P.xB, P.hB,
                                                     nullptr, P.zB,
                                                     P.coB + (blockIdx.x - P.cA) * 32,
                                                     blockIdx.y, 0, xls);
}

// Encoder CAND duo (h-cols only, 4 chunks): M-split 448-thread form.
__global__ __launch_bounds__(448, 3)
void diffuse_duo_c(DuoDP P)
{
    __shared__ __align__(16) unsigned xls[32 * XST];
    if ((int)blockIdx.x < P.cA)
        diffuse_body<2, 66, 160, true, false, 448>(P.ssh, P.ssl, P.xA, P.hA,
                                                   P.ruA, P.zA,
                                                   P.coA + blockIdx.x * 32,
                                                   blockIdx.y, blockIdx.z, xls);
    else
        diffuse_body<64, 128, 256, true, true, 448>(P.ssh, P.ssl, P.xB, P.hB,
                                                    P.ruB, P.zB,
                                                    P.coB + (blockIdx.x - P.cA) * 32,
                                                    blockIdx.y, blockIdx.z, xls);
}

// Decoder slot-1 duo: A = L0 gate-diffusion (DIN=1,F=65, all cols),
// B = L1 gate-diffusion h-columns (depend only on previous step's h1).
// M-split 448-thread form.
__global__ __launch_bounds__(448, 3)
void diffuse_duo_dec(DuoDP P)
{
    __shared__ __align__(16) unsigned xls[32 * XST];
    if ((int)blockIdx.x < P.cA)
        diffuse_body<1, 65, 160, false, false, 448>(P.ssh, P.ssl, P.xA, P.hA,
                                                    nullptr, P.zA,
                                                    P.coA + blockIdx.x * 32,
                                                    blockIdx.y, blockIdx.z, xls);
    else
        diffuse_body<64, 128, 256, false, true, 448>(P.ssh, P.ssl, P.xB, P.hB,
                                                     nullptr, P.zB,
                                                     P.coB + (blockIdx.x - P.cA) * 32,
                                                     blockIdx.y, blockIdx.z, xls);
}

struct DuoGP {
    const unsigned* zA; const float *xA, *hA;
    const short8 *WhA, *WlA; const float* bA; float* ruA;
    const unsigned* zB; const float *xB, *hB;
    const short8 *WhB, *WlB; const float* bB; float* ruB;
};

__global__ __launch_bounds__(256)
void gate_duo(DuoGP P)
{
    if (blockIdx.z == 0)
        gate_body<2, 66, 3, 5, false>(P.zA, P.xA, P.hA, P.WhA, P.WlA, P.bA,
                                      P.ruA, blockIdx.x, blockIdx.y * 4);
    else
        gate_body<64, 128, 4, 8, true>(P.zB, P.xB, P.hB, P.WhB, P.WlB, P.bB,
                                       P.ruB, blockIdx.x, blockIdx.y * 4);
}

struct DuoCP {
    const unsigned* zA; const float *xA, *hA, *ruA;
    const short8 *WhA, *WlA; const float* bA; float* hoA;
    const unsigned* zB; const float *xB, *hB, *ruB;
    const short8 *WhB, *WlB; const float* bB; float* hoB;
};

__global__ __launch_bounds__(256)
void cand_duo(DuoCP P)
{
    if (blockIdx.z == 0)
        cand_body<2, 66, 3, 5, false>(P.zA, P.xA, P.hA, P.ruA, P.WhA, P.WlA,
                                      P.bA, P.hoA, blockIdx.x, blockIdx.y * 2);
    else
        cand_body<64, 128, 4, 8, true>(P.zB, P.xB, P.hB, P.ruB, P.WhB, P.WlB,
                                       P.bB, P.hoB, blockIdx.x, blockIdx.y * 2);
}

// ---------------- host launcher ----------------

extern "C" void kernel_launch(void* const* d_in, const int* in_sizes, int n_in,
                              void* d_out, int out_size, void* d_ws, size_t ws_size,
                              hipStream_t stream)
{
    const float* inputs = (const float*)d_in[0];
    const float* S      = (const float*)d_in[1];
    const float* Wt[4][4];
    for (int l = 0; l < 4; ++l)
        for (int j = 0; j < 4; ++j)
            Wt[l][j] = (const float*)d_in[2 + l * 4 + j];
    const float* pW = (const float*)d_in[18];
    const float* pb = (const float*)d_in[19];
    float* out = (float*)d_out;

    // workspace layout (ping-pong h; y-only zcat)
    float*    ws     = (float*)d_ws;
    float*    H0[2]  = {ws, ws + (size_t)BN * U};
    float*    H1[2]  = {ws + 2 * (size_t)BN * U, ws + 3 * (size_t)BN * U};
    float*    dec_in = ws + 4 * (size_t)BN * U;            // BN
    float*    ruA    = dec_in + BN;                        // BN*128
    float*    ruB    = ruA + (size_t)BN * 128;             // BN*128
    unsigned* zcatA  = (unsigned*)(ruB + (size_t)BN * 128);  // BN*160
    unsigned* zcatB  = zcatA + (size_t)BN * 160;             // BN*256
    float*    S2     = (float*)(zcatB + (size_t)BN * 256);   // N*N
    char*     pp     = (char*)(S2 + (size_t)N * N);
    pp = (char*)(((uintptr_t)pp + 15) & ~(uintptr_t)15);

    short* ssh = (short*)pp;                       // 42*11*64*8 shorts
    short* ssl = ssh + (size_t)SSTIL * SSKC * 64 * 8;
    char*  wpbase = (char*)(ssl + (size_t)SSTIL * SSKC * 64 * 8);

    // K layouts: [z0 pad | y1 | y2 pad]; L0: 3+5 kc = 256, L1: 4+8 kc = 384
    const int Fs[4]   = {66, 128, 65, 128};
    const int KPs[4]  = {256, 384, 256, 384};
    const int Z0s[4]  = {3, 4, 3, 4};
    short *Wgh[4], *Wgl[4], *Wch[4], *Wcl[4];
    size_t off = 0;
    for (int l = 0; l < 4; ++l) {
        const size_t ge = (size_t)KPs[l] * 128, ce = (size_t)KPs[l] * 64;
        Wgh[l] = (short*)(wpbase + off); off += ge * 2;
        Wgl[l] = (short*)(wpbase + off); off += ge * 2;
        Wch[l] = (short*)(wpbase + off); off += ce * 2;
        Wcl[l] = (short*)(wpbase + off); off += ce * 2;
    }

    // zero state + zcat (first-use NaN-safety; pads stay finite thereafter)
    const long zn = (long)BN * (4 * U) + BN + (long)BN * 256 + (long)BN * (160 + 256);
    zero_kernel<<<2048, 256, 0, stream>>>((unsigned*)ws, zn);

    s2_build<<<N, 256, 0, stream>>>(S, S2);
    prepack_ss<<<dim3(SSTIL, SSKC), 64, 0, stream>>>(S, S2, ssh, ssl);
    for (int l = 0; l < 4; ++l) {
        prepack_w<<<dim3(KPs[l] / 32, 8), 64, 0, stream>>>(Wt[l][0], Wgh[l], Wgl[l],
                                                           Fs[l], 128, 8, Z0s[l]);
        prepack_w<<<dim3(KPs[l] / 32, 4), 64, 0, stream>>>(Wt[l][2], Wch[l], Wcl[l],
                                                           Fs[l], 64, 4, Z0s[l]);
    }

    const short8* SSH = (const short8*)ssh;
    const short8* SSL = (const short8*)ssl;
    int p0 = 0, p1 = 0;

    // -------- encoder: software-pipelined (cell0 step s || cell1 step s-1) ----
    for (int s = 0; s <= T; ++s) {
        const float* x0 = inputs + (size_t)s * BN * 2;
        const bool a = (s < T), b1 = (s >= 1);
        if (a && b1) {
            DuoDP dp{SSH, SSL, x0, H0[p0], nullptr, zcatA,
                     H0[p0], H1[p1], nullptr, zcatB, 3, 0, 0};
            diffuse_duo_g<<<dim3(7, B), 896, 0, stream>>>(dp);
            DuoGP gp{zcatA, x0, H0[p0], (short8*)Wgh[0], (short8*)Wgl[0], Wt[0][1], ruA,
                     zcatB, H0[p0], H1[p1], (short8*)Wgh[1], (short8*)Wgl[1], Wt[1][1], ruB};
            gate_duo<<<dim3(BN / 64, 2, 2), 256, 0, stream>>>(gp);
            // cand diffusion: h-cols only (x-col y's reused from gate pass)
            DuoDP dp2{SSH, SSL, x0, H0[p0], ruA, zcatA,
                      H0[p0], H1[p1], ruB, zcatB, 2, 2, 64};
            diffuse_duo_c<<<dim3(4, B, 2), 448, 0, stream>>>(dp2);
            DuoCP cp{zcatA, x0, H0[p0], ruA, (short8*)Wch[0], (short8*)Wcl[0], Wt[0][3], H0[p0 ^ 1],
                     zcatB, H0[p0], H1[p1], ruB, (short8*)Wch[1], (short8*)Wcl[1], Wt[1][3], H1[p1 ^ 1]};
            cand_duo<<<dim3(BN / 64, 2, 2), 256, 0, stream>>>(cp);
            p0 ^= 1; p1 ^= 1;
        } else if (a) {  // s == 0: cell0 solo; h0 == 0 so h-col y's are zero
            // (matching the zero-initialized zcatA bit-for-bit) -> only chunk 0
            // of the gate diffusion is needed, and the cand diffusion (r*h = 0)
            // is skipped entirely.
            diffuse_solo<2, 66, 160, false, 0, false><<<dim3(1, B, 2), 448, 0, stream>>>(
                SSH, SSL, x0, H0[p0], nullptr, zcatA);
            gate_cell<2, 66, 3, 5, false><<<dim3(BN / 64, 2), 256, 0, stream>>>(
                zcatA, x0, H0[p0], (short8*)Wgh[0], (short8*)Wgl[0], Wt[0][1], ruA);
            cand_cell<2, 66, 3, 5, false><<<dim3(BN / 64, 2), 256, 0, stream>>>(
                zcatA, x0, H0[p0], ruA, (short8*)Wch[0], (short8*)Wcl[0], Wt[0][3], H0[p0 ^ 1]);
            p0 ^= 1;
        } else {         // s == T: cell1 drain
            diffuse_solo<64, 128, 256, false, 0, true><<<dim3(4, B, 2), 448, 0, stream>>>(
                SSH, SSL, H0[p0], H1[p1], nullptr, zcatB);
            gate_cell<64, 128, 4, 8, true><<<dim3(BN / 64, 2), 256, 0, stream>>>(
                zcatB, H0[p0], H1[p1], (short8*)Wgh[1], (short8*)Wgl[1], Wt[1][1], ruB);
            diffuse_solo<64, 128, 256, true, 64, true><<<dim3(2, B, 2), 448, 0, stream>>>(
                SSH, SSL, H0[p0], H1[p1], ruB, zcatB);
            cand_cell<64, 128, 4, 8, true><<<dim3(BN / 64, 2), 256, 0, stream>>>(
                zcatB, H0[p0], H1[p1], ruB, (short8*)Wch[1], (short8*)Wcl[1], Wt[1][3], H1[p1 ^ 1]);
            p1 ^= 1;
        }
    }

    // -------- decoder: slot1 = [L0 gate-diff ∥ L1 h-col gate-diff] --------
    // L0 lives in zcatA (pitch 160), L1 in zcatB (pitch 256).
    for (int hz = 0; hz < HZ; ++hz) {
        DuoDP dd{SSH, SSL, dec_in, H0[p0], nullptr, zcatA,
                 H0[p0], H1[p1], nullptr, zcatB, 3, 0, 64};
        diffuse_duo_dec<<<dim3(5, B, 2), 448, 0, stream>>>(dd);
        gate_cell<1, 65, 3, 5, false><<<dim3(BN / 64, 2), 256, 0, stream>>>(
            zcatA, dec_in, H0[p0], (short8*)Wgh[2], (short8*)Wgl[2], Wt[2][1], ruA);
        // L0 cand diffusion: h-cols only (cols 1..64)
        diffuse_solo<1, 65, 160, true, 1, false><<<dim3(2, B, 2), 448, 0, stream>>>(
            SSH, SSL, dec_in, H0[p0], ruA, zcatA);
        cand_cell<1, 65, 3, 5, false><<<dim3(BN / 64, 2), 256, 0, stream>>>(
            zcatA, dec_in, H0[p0], ruA, (short8*)Wch[2], (short8*)Wcl[2], Wt[2][3], H0[p0 ^ 1]);
        p0 ^= 1;
        // L1 gate-diff: x-cols only (h-cols hoisted into slot 1)
        diffuse_solo<64, 128, 256, false, 0, true><<<dim3(2, B, 2), 448, 0, stream>>>(
            SSH, SSL, H0[p0], H1[p1], nullptr, zcatB);
        gate_cell<64, 128, 4, 8, true><<<dim3(BN / 64, 2), 256, 0, stream>>>(
            zcatB, H0[p0], H1[p1], (short8*)Wgh[3], (short8*)Wgl[3], Wt[3][1], ruA);
        // L1 cand diffusion: h-cols only
        diffuse_solo<64, 128, 256, true, 64, true><<<dim3(2, B, 2), 448, 0, stream>>>(
            SSH, SSL, H0[p0], H1[p1], ruA, zcatB);
        cand_proj<<<BN / 64, 256, 0, stream>>>(
            zcatB, H0[p0], H1[p1], ruA, (short8*)Wch[3], (short8*)Wcl[3], Wt[3][3],
            H1[p1 ^ 1], pW, pb, out + (size_t)hz * BN, dec_in);
        p1 ^= 1;
    }
}